// Round 1
// baseline (7032.259 us; speedup 1.0000x reference)
//
#include <hip/hip_runtime.h>

#define V 256
#define H 2048
#define A 512
#define S 512

// ---------------- generic NT GEMM: C[m][n] = sum_k A[m*lda+k]*B[n*ldb+k] (+bias[n]) ----------------
// 64x64 tile, BK=16, 256 threads, 4x4 per thread. M%64==0, N%64==0, K%16==0 guaranteed by shapes.
__global__ __launch_bounds__(256) void gemm_nt(
    const float* __restrict__ Amat, int lda,
    const float* __restrict__ Bmat, int ldb,
    float* __restrict__ C, int ldc,
    const float* __restrict__ bias, int M, int N, int K)
{
    __shared__ float As[16][68];
    __shared__ float Bs[16][68];
    const int tid = threadIdx.x;
    const int tx = tid & 15;        // n-dir
    const int ty = tid >> 4;        // m-dir
    const int m0 = blockIdx.y * 64;
    const int n0 = blockIdx.x * 64;
    const int lr = tid >> 2;        // 0..63 row within tile
    const int lk = (tid & 3) * 4;   // 0,4,8,12 k within tile

    float acc[4][4] = {};
    for (int k0 = 0; k0 < K; k0 += 16) {
        float4 av = *(const float4*)(Amat + (size_t)(m0 + lr) * lda + k0 + lk);
        float4 bv = *(const float4*)(Bmat + (size_t)(n0 + lr) * ldb + k0 + lk);
        __syncthreads();   // previous iter's LDS reads done
        As[lk+0][lr] = av.x; As[lk+1][lr] = av.y; As[lk+2][lr] = av.z; As[lk+3][lr] = av.w;
        Bs[lk+0][lr] = bv.x; Bs[lk+1][lr] = bv.y; Bs[lk+2][lr] = bv.z; Bs[lk+3][lr] = bv.w;
        __syncthreads();
        #pragma unroll
        for (int k = 0; k < 16; ++k) {
            float a4[4], b4[4];
            #pragma unroll
            for (int i = 0; i < 4; ++i) a4[i] = As[k][ty*4+i];
            #pragma unroll
            for (int j = 0; j < 4; ++j) b4[j] = Bs[k][tx*4+j];
            #pragma unroll
            for (int i = 0; i < 4; ++i)
                #pragma unroll
                for (int j = 0; j < 4; ++j) acc[i][j] += a4[i] * b4[j];
        }
    }
    #pragma unroll
    for (int i = 0; i < 4; ++i) {
        const int m = m0 + ty*4 + i;
        #pragma unroll
        for (int j = 0; j < 4; ++j) {
            const int n = n0 + tx*4 + j;
            float v = acc[i][j];
            if (bias) v += bias[n];
            C[(size_t)m * ldc + n] = v;
        }
    }
}

// ---------------- encoder step: h_out[i] = tanh(accx[i] + sum_j W_enc[i][V+j]*h_prev[j]) ----------------
__global__ __launch_bounds__(256) void enc_step(
    const float* __restrict__ W_enc,   // (H, V+H)
    const float* __restrict__ accx,    // precomputed x-part + bias, length H
    const float* __restrict__ h_prev,  // length H (ignored when t==0)
    float* __restrict__ h_out, int t)
{
    const int wave = threadIdx.x >> 6;
    const int lane = threadIdx.x & 63;
    const int row  = blockIdx.x * 4 + wave;     // 0..H-1
    float acc = 0.f;
    if (t > 0) {
        const float4* w4 = (const float4*)(W_enc + (size_t)row * (V + H) + V);
        const float4* h4 = (const float4*)h_prev;
        #pragma unroll
        for (int it = 0; it < H/256; ++it) {
            float4 w = w4[lane + it*64];
            float4 hh = h4[lane + it*64];
            acc += w.x*hh.x + w.y*hh.y + w.z*hh.z + w.w*hh.w;
        }
    }
    for (int off = 32; off; off >>= 1) acc += __shfl_down(acc, off);
    if (lane == 0) h_out[row] = tanhf(acc + accx[row]);
}

// ---------------- decoder P1: dec_proj[a] = Wa_dec[a]·h ; acc_h[i] = W_dec[i, V+H:]·h ----------------
__global__ __launch_bounds__(256) void dec_p1(
    const float* __restrict__ Wa_dec,  // (A,H)
    const float* __restrict__ W_dec,   // (H, V+2H)
    const float* __restrict__ h_prev,
    float* __restrict__ dec_proj, float* __restrict__ acc_h)
{
    const int wave = threadIdx.x >> 6;
    const int lane = threadIdx.x & 63;
    const int r    = blockIdx.x * 4 + wave;     // 0..A+H-1
    const float* wr = (r < A) ? (Wa_dec + (size_t)r * H)
                              : (W_dec + (size_t)(r - A) * (V + 2*H) + V + H);
    const float4* w4 = (const float4*)wr;
    const float4* h4 = (const float4*)h_prev;
    float acc = 0.f;
    #pragma unroll
    for (int it = 0; it < H/256; ++it) {
        float4 w = w4[lane + it*64];
        float4 hh = h4[lane + it*64];
        acc += w.x*hh.x + w.y*hh.y + w.z*hh.z + w.w*hh.w;
    }
    for (int off = 32; off; off >>= 1) acc += __shfl_down(acc, off);
    if (lane == 0) { if (r < A) dec_proj[r] = acc; else acc_h[r - A] = acc; }
}

// ---------------- decoder P2: e[s] = exp( sum_a tanh(enc_proj[s][a]+dec_proj[a]) * v_a[a] ) ----------------
__global__ __launch_bounds__(256) void dec_p2(
    const float* __restrict__ enc_proj,  // (S,A)
    const float* __restrict__ dec_proj,  // (A)
    const float* __restrict__ v_a,       // (A)
    float* __restrict__ e)
{
    const int wave = threadIdx.x >> 6;
    const int lane = threadIdx.x & 63;
    const int s    = blockIdx.x * 4 + wave;     // 0..S-1
    const float4* ep = (const float4*)(enc_proj + (size_t)s * A);
    const float4* dp = (const float4*)dec_proj;
    const float4* va = (const float4*)v_a;
    float acc = 0.f;
    #pragma unroll
    for (int it = 0; it < A/256; ++it) {
        float4 p = ep[lane + it*64];
        float4 d = dp[lane + it*64];
        float4 v = va[lane + it*64];
        acc += tanhf(p.x+d.x)*v.x + tanhf(p.y+d.y)*v.y + tanhf(p.z+d.z)*v.z + tanhf(p.w+d.w)*v.w;
    }
    for (int off = 32; off; off >>= 1) acc += __shfl_down(acc, off);
    if (lane == 0) e[s] = expf(acc);
}

// ---------------- decoder P3: h_out[i] = tanh(accx[i] + acc_h[i] + (WcT[i]·e)/Z) ----------------
__global__ __launch_bounds__(256) void dec_p3(
    const float* __restrict__ WcT,   // (H,S)  WcT[i][s] = (W_c @ enc_states[s])[i]
    const float* __restrict__ e,     // (S) unnormalized softmax weights
    const float* __restrict__ accx,  // x-part + bias for this t, length H
    const float* __restrict__ acc_h, // W_h part, length H
    float* __restrict__ h_out)
{
    __shared__ __align__(16) float es[S];
    __shared__ float zred[4];
    const int tid  = threadIdx.x;
    const int wave = tid >> 6;
    const int lane = tid & 63;

    float part = 0.f;
    for (int s = tid; s < S; s += 256) { float v = e[s]; es[s] = v; part += v; }
    for (int off = 32; off; off >>= 1) part += __shfl_down(part, off);
    if (lane == 0) zred[wave] = part;
    __syncthreads();
    const float Zinv = 1.f / (zred[0] + zred[1] + zred[2] + zred[3]);

    const int row = blockIdx.x * 4 + wave;      // 0..H-1
    const float4* w4 = (const float4*)(WcT + (size_t)row * S);
    const float4* e4 = (const float4*)es;
    float acc = 0.f;
    #pragma unroll
    for (int it = 0; it < S/256; ++it) {
        float4 w = w4[lane + it*64];
        float4 ev = e4[lane + it*64];
        acc += w.x*ev.x + w.y*ev.y + w.z*ev.z + w.w*ev.w;
    }
    for (int off = 32; off; off >>= 1) acc += __shfl_down(acc, off);
    if (lane == 0) h_out[row] = tanhf(accx[row] + acc_h[row] + acc * Zinv);
}

extern "C" void kernel_launch(void* const* d_in, const int* in_sizes, int n_in,
                              void* d_out, int out_size, void* d_ws, size_t ws_size,
                              hipStream_t stream) {
    const float* x_enc  = (const float*)d_in[0];   // (S,V)
    const float* x_dec  = (const float*)d_in[1];   // (S,V)
    const float* W_enc  = (const float*)d_in[2];   // (H, V+H)
    const float* b_enc  = (const float*)d_in[3];   // (H)
    const float* Wa_enc = (const float*)d_in[4];   // (A,H)
    const float* Wa_dec = (const float*)d_in[5];   // (A,H)
    const float* v_a    = (const float*)d_in[6];   // (A)
    const float* W_dec  = (const float*)d_in[7];   // (H, V+2H)
    const float* b_dec  = (const float*)d_in[8];   // (H)
    const float* W_out  = (const float*)d_in[9];   // (V,H)
    const float* b_out  = (const float*)d_in[10];  // (V)
    float* out = (float*)d_out;

    float* ws         = (float*)d_ws;
    float* accx_enc   = ws;                          // S*H
    float* enc_states = accx_enc + (size_t)S*H;      // S*H
    float* enc_proj   = enc_states + (size_t)S*H;    // S*A
    float* WcT        = enc_proj + (size_t)S*A;      // H*S
    float* accx_dec   = WcT + (size_t)H*S;           // S*H
    float* h_dec      = accx_dec + (size_t)S*H;      // S*H
    float* dec_proj   = h_dec + (size_t)S*H;         // A
    float* acc_h      = dec_proj + A;                // H
    float* evec       = acc_h + H;                   // S

    dim3 b256(256);

    // accx_enc = x_enc @ W_enc[:, :V].T + b_enc   (M=S, N=H, K=V)
    gemm_nt<<<dim3(H/64, S/64), b256, 0, stream>>>(x_enc, V, W_enc, V+H, accx_enc, H, b_enc, S, H, V);

    // encoder scan
    for (int t = 0; t < S; ++t) {
        enc_step<<<dim3(H/4), b256, 0, stream>>>(
            W_enc, accx_enc + (size_t)t*H,
            t ? enc_states + (size_t)(t-1)*H : accx_enc /*ignored*/,
            enc_states + (size_t)t*H, t);
    }

    // enc_proj = enc_states @ Wa_enc.T   (M=S, N=A, K=H)
    gemm_nt<<<dim3(A/64, S/64), b256, 0, stream>>>(enc_states, H, Wa_enc, H, enc_proj, A, nullptr, S, A, H);

    // WcT[i][s] = sum_j W_dec[i][V+j] * enc_states[s][j]   (M=H, N=S, K=H)
    gemm_nt<<<dim3(S/64, H/64), b256, 0, stream>>>(W_dec + V, V+2*H, enc_states, H, WcT, S, nullptr, H, S, H);

    // accx_dec = x_dec @ W_dec[:, :V].T + b_dec   (M=S, N=H, K=V)
    gemm_nt<<<dim3(H/64, S/64), b256, 0, stream>>>(x_dec, V, W_dec, V+2*H, accx_dec, H, b_dec, S, H, V);

    // decoder scan
    for (int t = 0; t < S; ++t) {
        const float* hp = t ? h_dec + (size_t)(t-1)*H : enc_states + (size_t)(S-1)*H;
        dec_p1<<<dim3((A+H)/4), b256, 0, stream>>>(Wa_dec, W_dec, hp, dec_proj, acc_h);
        dec_p2<<<dim3(S/4),     b256, 0, stream>>>(enc_proj, dec_proj, v_a, evec);
        dec_p3<<<dim3(H/4),     b256, 0, stream>>>(WcT, evec, accx_dec + (size_t)t*H, acc_h, h_dec + (size_t)t*H);
    }

    // logits = h_dec @ W_out.T + b_out   (M=S, N=V, K=H) -> d_out
    gemm_nt<<<dim3(V/64, S/64), b256, 0, stream>>>(h_dec, H, W_out, H, out, V, b_out, S, V, H);
}